// Round 12
// baseline (75.232 us; speedup 1.0000x reference)
//
#include <hip/hip_runtime.h>

// Problem constants (fixed by reference setup_inputs()).
#define BB 8
#define CC 256
#define EE 18000
#define TT 4500
#define BT (BB * TT)     // 36000
#define BE (BB * EE)     // 144000
#define NT 1024          // pool threads (16 waves)
#define W  18            // positions per thread; 1000 threads cover 18000 positions
#define PW (NT * W)      // 18432 float2 slots = 147456 B LDS -> 1 block/CU

// ---------------- setup ----------------------------------------------------

__global__ void zero_counts_kernel(int* __restrict__ counts) {
    int i = blockIdx.x * blockDim.x + threadIdx.x;
    if (i < BT) counts[i] = 0;
}

__global__ void count_kernel(const int* __restrict__ gid, int* __restrict__ counts) {
    int i = blockIdx.x * blockDim.x + threadIdx.x;
    if (i < BE) {
        int b = i / EE;
        atomicAdd(&counts[b * TT + gid[i]], 1);
    }
}

// one block per batch: exclusive scan of counts -> cursor (scatter cursor,
// base b*EE) and epilogue table tab[g] = {start | end<<16, bits(inv)}.
__global__ __launch_bounds__(1024) void scan_kernel(const int* __restrict__ counts,
                                                    int* __restrict__ cursor,
                                                    uint2* __restrict__ tab) {
    __shared__ int part[1024];
    const int b = blockIdx.x;
    const int t = threadIdx.x;
    const int CHUNK = 5;                          // 1024*5 >= 4500
    int lo = t * CHUNK; if (lo > TT) lo = TT;
    int hi = lo + CHUNK; if (hi > TT) hi = TT;
    int s = 0;
    for (int i = lo; i < hi; ++i) s += counts[b * TT + i];
    part[t] = s;
    __syncthreads();
    for (int d = 1; d < 1024; d <<= 1) {
        int v = (t >= d) ? part[t - d] : 0;
        __syncthreads();
        part[t] += v;
        __syncthreads();
    }
    int run = part[t] - s;                        // per-batch exclusive prefix
    for (int i = lo; i < hi; ++i) {
        int cnt = counts[b * TT + i];
        cursor[b * TT + i] = b * EE + run;
        int en = run + cnt;
        float inv = cnt ? 1.0f / (float)cnt : 0.0f;
        tab[b * TT + i] = make_uint2((unsigned)run | ((unsigned)en << 16),
                                     __float_as_uint(inv));
        run = en;
    }
}

// atomic CSR scatter: prank16[e] = raw CSR position of edge e in batch b
__global__ void scatter_kernel(const int* __restrict__ gid,
                               int* __restrict__ cursor,
                               unsigned short* __restrict__ prank16) {
    int i = blockIdx.x * blockDim.x + threadIdx.x;
    if (i < BE) {
        int b = i / EE;
        int p = atomicAdd(&cursor[b * TT + gid[i]], 1) - b * EE;
        prank16[i] = (unsigned short)p;           // < 18000
    }
}

// ---------------- main: 2 channels per block, float2-packed ----------------
// One block per (b, channel-pair), 1024 threads, 147456 B LDS -> 1 block/CU.
// Scatter: one ds_write_b64 {v_c0, v_c1} per edge -- halves LDS issue slots,
// rank16 traffic, and block count vs 1-channel blocks. Phase A: 9x b128 read
// (2 positions x 2 channels); dual running sums; dual shfl scan. Phase C:
// 9x b128 prefix write (both channels). Epilogue: float2 gathers (both
// channels per LDS op), two coalesced float4 stores. Threads 1000..1023 scan
// garbage windows: pollute only wsum[15] (never consumed; shfl_up only pulls
// from lower lanes) and vals2[18000..18432) (never read).

__global__ __launch_bounds__(1024, 4) void pool_kernel(const float* __restrict__ fe,
                                                       const unsigned short* __restrict__ prank16,
                                                       const uint2* __restrict__ tab,
                                                       float* __restrict__ out) {
    __shared__ float2 vals2[PW];                  // 147456 B
    __shared__ float2 wsum[16];
    const int b   = blockIdx.x >> 7;              // 128 channel-pairs per batch
    const int cp  = blockIdx.x & 127;
    const int c0  = cp << 1;
    const int tid = threadIdx.x;
    const int wv  = tid >> 6;
    const int ln  = tid & 63;

    // scatter both channels' rows into CSR order (coalesced float4 + ushort4)
    const float4*  feA = (const float4*)(fe + (size_t)(b * CC + c0) * EE);
    const float4*  feB = (const float4*)(fe + (size_t)(b * CC + c0 + 1) * EE);
    const ushort4* rk4 = (const ushort4*)(prank16 + (size_t)b * EE);
#pragma unroll
    for (int i = 0; i < 5; ++i) {                 // 5*1024 = 5120 >= 4500
        int idx = tid + (i << 10);
        if (idx < EE / 4) {
            float4  va = feA[idx];
            float4  vb = feB[idx];
            ushort4 r  = rk4[idx];
            vals2[r.x] = make_float2(va.x, vb.x);
            vals2[r.y] = make_float2(va.y, vb.y);
            vals2[r.z] = make_float2(va.z, vb.z);
            vals2[r.w] = make_float2(va.w, vb.w);
        }
    }
    __syncthreads();

    // phase A: 9x b128 loads (2 positions x 2 channels); intra-pair prefixes
    const int base = W * tid;                     // float2 units; 144 B stride
    float4 pv[9];
    float2 csum[9];
#pragma unroll
    for (int k = 0; k < 9; ++k) {
        float4 v = *reinterpret_cast<const float4*>(&vals2[base + (k << 1)]);
        float q1x = v.x + v.z;                    // ch0: incl prefix of 2nd pos
        float q1y = v.y + v.w;                    // ch1
        pv[k] = make_float4(v.x, v.y, q1x, q1y);
        csum[k] = make_float2(q1x, q1y);
    }
    float2 t01 = make_float2(csum[0].x + csum[1].x, csum[0].y + csum[1].y);
    float2 t23 = make_float2(csum[2].x + csum[3].x, csum[2].y + csum[3].y);
    float2 t45 = make_float2(csum[4].x + csum[5].x, csum[4].y + csum[5].y);
    float2 t67 = make_float2(csum[6].x + csum[7].x, csum[6].y + csum[7].y);
    const float sumx = ((t01.x + t23.x) + (t45.x + t67.x)) + csum[8].x;
    const float sumy = ((t01.y + t23.y) + (t45.y + t67.y)) + csum[8].y;

    // per-wave inclusive shfl scan of window sums (both channels)
    float scx = sumx, scy = sumy;
#pragma unroll
    for (int d = 1; d < 64; d <<= 1) {
        float ox = __shfl_up(scx, d, 64);
        float oy = __shfl_up(scy, d, 64);
        if (ln >= d) { scx += ox; scy += oy; }
    }
    if (ln == 63) wsum[wv] = make_float2(scx, scy);
    __syncthreads();

    // cross-wave exclusive offset
    float crx = 0.0f, cry = 0.0f;
#pragma unroll
    for (int j = 0; j < 16; ++j) {
        float2 tw = wsum[j];                      // broadcast read
        if (j < wv) { crx += tw.x; cry += tw.y; }
    }

    // phase C: add running offsets, 9x b128 stores (both channels)
    float offx = crx + (scx - sumx);
    float offy = cry + (scy - sumy);
#pragma unroll
    for (int k = 0; k < 9; ++k) {
        float4 p = pv[k];
        *reinterpret_cast<float4*>(&vals2[base + (k << 1)]) =
            make_float4(p.x + offx, p.y + offy, p.z + offx, p.w + offy);
        offx += csum[k].x;
        offy += csum[k].y;
    }
    __syncthreads();

    // epilogue: 4 consecutive groups per slot; both channels per gather
    const uint2* tbB   = tab + b * TT;
    float*       outb0 = out + (size_t)(b * CC + c0) * TT;
    float*       outb1 = outb0 + TT;
    for (int s = tid; s < TT / 4; s += NT) {      // 1125 slots
        const uint2* tb = tbB + (s << 2);
        uint4 qA = *reinterpret_cast<const uint4*>(tb);      // groups 4s,4s+1
        uint4 qB = *reinterpret_cast<const uint4*>(tb + 2);  // groups 4s+2,4s+3

        unsigned se0 = qA.x, se1 = qA.z, se2 = qB.x, se3 = qB.z;
        float iv0 = __uint_as_float(qA.y), iv1 = __uint_as_float(qA.w);
        float iv2 = __uint_as_float(qB.y), iv3 = __uint_as_float(qB.w);

        unsigned st0 = se0 & 0xffffu;
        unsigned en0 = se0 >> 16, en1 = se1 >> 16, en2 = se2 >> 16, en3 = se3 >> 16;

        // P(pos) = pos ? vals2[pos-1] : 0; reads clamped to valid range
        float2 Pp = vals2[(st0 ? st0 : 1u) - 1u]; if (!st0) Pp = make_float2(0.f, 0.f);
        float2 P0 = vals2[(en0 ? en0 : 1u) - 1u]; if (!en0) P0 = make_float2(0.f, 0.f);
        float2 P1 = vals2[(en1 ? en1 : 1u) - 1u]; if (!en1) P1 = make_float2(0.f, 0.f);
        float2 P2 = vals2[(en2 ? en2 : 1u) - 1u]; if (!en2) P2 = make_float2(0.f, 0.f);
        float2 P3 = vals2[(en3 ? en3 : 1u) - 1u]; if (!en3) P3 = make_float2(0.f, 0.f);

        float4 o0, o1;                            // st(g+1) == en(g): chain
        o0.x = (P0.x - Pp.x) * iv0;  o1.x = (P0.y - Pp.y) * iv0;
        o0.y = (P1.x - P0.x) * iv1;  o1.y = (P1.y - P0.y) * iv1;
        o0.z = (P2.x - P1.x) * iv2;  o1.z = (P2.y - P1.y) * iv2;
        o0.w = (P3.x - P2.x) * iv3;  o1.w = (P3.y - P2.y) * iv3;

        *reinterpret_cast<float4*>(outb0 + (s << 2)) = o0;
        *reinterpret_cast<float4*>(outb1 + (s << 2)) = o1;
    }
}

extern "C" void kernel_launch(void* const* d_in, const int* in_sizes, int n_in,
                              void* d_out, int out_size, void* d_ws, size_t ws_size,
                              hipStream_t stream) {
    const float* fe  = (const float*)d_in[0];
    const int*   gid = (const int*)d_in[1];
    float*       out = (float*)d_out;

    // ws: counts[BT] i32 | cursor[BT] i32 | tab[BT] uint2 | prank16[BE] u16
    int*            counts  = (int*)d_ws;
    int*            cursor  = counts + BT;
    uint2*          tab     = (uint2*)(cursor + BT);   // byte offset 288000, 16B-aligned
    unsigned short* prank16 = (unsigned short*)(tab + BT);

    zero_counts_kernel<<<(BT + 255) / 256, 256, 0, stream>>>(counts);
    count_kernel<<<(BE + 255) / 256, 256, 0, stream>>>(gid, counts);
    scan_kernel<<<BB, 1024, 0, stream>>>(counts, cursor, tab);
    scatter_kernel<<<(BE + 255) / 256, 256, 0, stream>>>(gid, cursor, prank16);
    pool_kernel<<<BB * (CC / 2), 1024, 0, stream>>>(fe, prank16, tab, out);
}